// Round 8
// baseline (249.105 us; speedup 1.0000x reference)
//
#include <hip/hip_runtime.h>
#include <hip/hip_bf16.h>
#include <math.h>
#include <stdint.h>
#include <string.h>

#define NEG_SLOPE 0.2f
#define BN_EPS 1e-5f

typedef __attribute__((ext_vector_type(8))) short short8;
typedef __attribute__((ext_vector_type(4))) float float4v;

static __device__ __forceinline__ unsigned short f2bf(float f) {
    union { float f; unsigned u; } v; v.f = f;
    unsigned r = (v.u + 0x7fffu + ((v.u >> 16) & 1u)) >> 16;  // RNE
    return (unsigned short)r;
}
static __device__ __forceinline__ float bf2f(unsigned short u) {
    union { unsigned u; float f; } v; v.u = ((unsigned)u) << 16;
    return v.f;
}

// ---------------------------------------------------------------------------
// R23 = R18 structure (gather reverted to R16-proven after 6 null/negative
// gather experiments) + query-bucketed, XCD-colocated link predictor.
//   D1 = zero_init: bcur[nb+1] + qcur[nb] (no hipMemsetAsync — R17 crash).
//   D2 = prep_scatter: W-transpose + BN || edge scatter || QUERY scatter
//        (bucket queries by e0>>8; record = e1<<32 | (e0&255)<<24 | q).
//   D3 = gemm1_fill: conv1 GEMM (+scores) || edge-bucket CSR fill.
//   D7 = link_pred: 4 blocks per query-bucket, all on ONE XCD (blockIdx%8
//        round-robin) so the bucket's 256 A-rows (64KB) stay L2-hot; e1
//        comes from the record (no dependent E1[q] load).
// R19 lesson: per-node work per-node. R20: 512-thr link_pred blocks.
// R21: never trade VGPR/occupancy for rows-in-flight in the gather.
// ---------------------------------------------------------------------------
#define BK_CAP 8192          // slots per edge bucket (~4096 expected)
#define QB_CAP 2048          // slots per query bucket (~1020 expected)
#define BK_EPB 4096          // items per block in scatter phases
#define LP_RS 136            // LDS row stride in bf16 elements (272 bytes)

__global__ __launch_bounds__(256) void zero_init(int* __restrict__ p, int n) {
    int i = threadIdx.x + blockIdx.x * 256;
    if (i < n) p[i] = 0;
}

// ---- edge scatter body ----------------------------------------------------
static __device__ __forceinline__ void scatter_body(
    int* lcnt, int* lbase, int blk,
    const int* __restrict__ src, const int* __restrict__ dst,
    int* __restrict__ bcur, unsigned int* __restrict__ bucket, int E) {
    int t = threadIdx.x;
    int e0 = blk * BK_EPB;
    lcnt[t] = 0;
    __syncthreads();

    int es[16], ed[16];
#pragma unroll
    for (int u = 0; u < 16; ++u) {
        int i = e0 + u * 256 + t;
        if (i < E) {
            es[u] = src[i];
            ed[u] = dst[i];
            atomicAdd(&lcnt[ed[u] >> 8], 1);
        } else {
            ed[u] = -1;
        }
    }
    __syncthreads();
    int c = lcnt[t];
    if (c > 0) lbase[t] = atomicAdd(&bcur[t], c);
    __syncthreads();
    lcnt[t] = 0;
    __syncthreads();
#pragma unroll
    for (int u = 0; u < 16; ++u) {
        if (ed[u] >= 0) {
            int bin = ed[u] >> 8;
            int r = atomicAdd(&lcnt[bin], 1);
            int slot = lbase[bin] + r;
            if (slot < BK_CAP)
                bucket[(size_t)bin * BK_CAP + slot] =
                    ((unsigned)(ed[u] & 255) << 24) | (unsigned)es[u];
        }
    }
}

// ---- query scatter body (buckets by e0>>8; embeds e1 in the record) -------
static __device__ __forceinline__ void qscatter_body(
    int* lcnt, int* lbase, int blk,
    const int* __restrict__ E0, const int* __restrict__ E1,
    int* __restrict__ qcur, unsigned long long* __restrict__ qbucket, int Q) {
    int t = threadIdx.x;
    int q0 = blk * BK_EPB;
    lcnt[t] = 0;
    __syncthreads();

    int a0[16], a1[16];
#pragma unroll
    for (int u = 0; u < 16; ++u) {
        int i = q0 + u * 256 + t;
        if (i < Q) {
            a0[u] = E0[i];
            a1[u] = E1[i];
            atomicAdd(&lcnt[a0[u] >> 8], 1);
        } else {
            a0[u] = -1;
        }
    }
    __syncthreads();
    int c = lcnt[t];
    if (c > 0) lbase[t] = atomicAdd(&qcur[t], c);
    __syncthreads();
    lcnt[t] = 0;
    __syncthreads();
#pragma unroll
    for (int u = 0; u < 16; ++u) {
        if (a0[u] >= 0) {
            int bin = a0[u] >> 8;
            int r = atomicAdd(&lcnt[bin], 1);
            int slot = lbase[bin] + r;
            int i = q0 + u * 256 + t;
            if (slot < QB_CAP)
                qbucket[(size_t)bin * QB_CAP + slot] =
                    ((unsigned long long)(unsigned)a1[u] << 32) |
                    ((unsigned)(a0[u] & 255) << 24) | (unsigned)i;
        }
    }
}

__global__ __launch_bounds__(256) void prep_scatter(
    const float* __restrict__ W1, const float* __restrict__ W2,
    const float* __restrict__ Wp1,
    unsigned short* __restrict__ wt1, unsigned short* __restrict__ wt2,
    unsigned short* __restrict__ wtp,
    const float* __restrict__ gamma, const float* __restrict__ beta,
    const float* __restrict__ rmean, const float* __restrict__ rvar,
    float* __restrict__ bnsc, float* __restrict__ bnsh,
    const int* __restrict__ src, const int* __restrict__ dst,
    int* __restrict__ bcur, unsigned int* __restrict__ bucket, int E,
    const int* __restrict__ E0, const int* __restrict__ E1,
    int* __restrict__ qcur, unsigned long long* __restrict__ qbucket,
    int Q, int nbs) {
    __shared__ int lcnt[256];
    __shared__ int lbase[256];
    int b = blockIdx.x;
    if (b < 192) {
        const float* W = (b < 64) ? W1 : (b < 128) ? W2 : Wp1;
        unsigned short* WT = (b < 64) ? wt1 : (b < 128) ? wt2 : wtp;
        int idx = (b & 63) * 256 + threadIdx.x;  // 16384 per matrix
        int k = idx >> 7, n = idx & 127;
        WT[n * 128 + k] = f2bf(W[idx]);
    } else if (b == 192) {
        if (threadIdx.x < 128) {
            int c = threadIdx.x;
            float s = gamma[c] * rsqrtf(rvar[c] + BN_EPS);
            bnsc[c] = s;
            bnsh[c] = beta[c] - rmean[c] * s;
        }
    } else if (b < 193 + nbs) {
        scatter_body(lcnt, lbase, b - 193, src, dst, bcur, bucket, E);
    } else {
        qscatter_body(lcnt, lbase, b - 193 - nbs, E0, E1, qcur, qbucket, Q);
    }
}

// ---- fill body (edge buckets -> CSR; blocks of gemm1_fill with b >= gblk) --
static __device__ __forceinline__ void fill_body(
    char* base, int b,
    const int* __restrict__ bcur, const unsigned int* __restrict__ bucket,
    int* __restrict__ gcnt,
    int* __restrict__ offs, int* __restrict__ ends,
    int* __restrict__ csr, int N) {
    unsigned int* rec = (unsigned int*)base;                 // BK_CAP * 4
    int* cnt = (int*)(base + BK_CAP * 4);
    int* sc  = cnt + 256;
    int* pb  = sc + 256;
    int t = threadIdx.x;
    const unsigned int* gb = &bucket[(size_t)b * BK_CAP];
    cnt[t] = 0;
    int c = bcur[b];
    if (c < 0) c = 0;          // defensive: never trust a poisoned counter
    if (c > BK_CAP) c = BK_CAP;
    if (t == 0) *pb = atomicAdd(gcnt, c);
    for (int i = t; i < c; i += 256) rec[i] = gb[i];
    __syncthreads();
    for (int i = t; i < c; i += 256) atomicAdd(&cnt[rec[i] >> 24], 1);
    __syncthreads();
    int v = cnt[t];
    sc[t] = v;
    __syncthreads();
    for (int d = 1; d < 256; d <<= 1) {
        int u = (t >= d) ? sc[t - d] : 0;
        __syncthreads();
        sc[t] += u;
        __syncthreads();
    }
    int myoff = *pb + sc[t] - v;
    int node = (b << 8) + t;
    if (node < N) {
        offs[node] = myoff;
        ends[node] = myoff + v;
    }
    cnt[t] = myoff;  // reuse as cursors
    __syncthreads();
    for (int i = t; i < c; i += 256) {
        unsigned int rv = rec[i];
        int r = atomicAdd(&cnt[rv >> 24], 1);
        csr[r] = (int)(rv & 0xffffffu);
    }
}

// ---------------------------------------------------------------------------
// H(bf16) = X @ W via MFMA bf16 (fp32 accum), node_scores fused in epilogue
// (per-node cost, amortized over N — R19 lesson).
// ---------------------------------------------------------------------------
template <bool BF16_IN>
static __device__ __forceinline__ void gemm_body(
    unsigned short* sA, unsigned short* sW, int bid,
    const void* __restrict__ Xv,
    const unsigned short* __restrict__ WT,  // [n][k] bf16 (pre-transposed)
    const float* __restrict__ a_src, const float* __restrict__ a_dst,
    unsigned short* __restrict__ H,         // bf16 out
    float* __restrict__ s_src, float* __restrict__ s_dst, int N)
{
    const float* Xf = (const float*)Xv;
    const unsigned short* Xh = (const unsigned short*)Xv;
    int tid = threadIdx.x;
    int r0 = bid * 128;

#pragma unroll
    for (int it = 0; it < 8; ++it) {
        int idx = it * 2048 + tid * 8;
        int n = idx >> 7, k = idx & 127;
        *(short8*)&sW[n * LP_RS + k] = *(const short8*)&WT[idx];
    }
#pragma unroll
    for (int it = 0; it < 16; ++it) {
        int r = it * 8 + (tid >> 5);
        int c = (tid & 31) * 4;
        int row = r0 + r;
        ushort4 u = make_ushort4(0, 0, 0, 0);
        if (row < N) {
            if (BF16_IN) {
                u = *(const ushort4*)&Xh[(size_t)row * 128 + c];
            } else {
                float4 x = *(const float4*)&Xf[(size_t)row * 128 + c];
                u.x = f2bf(x.x); u.y = f2bf(x.y); u.z = f2bf(x.z); u.w = f2bf(x.w);
            }
        }
        *(ushort4*)&sA[r * LP_RS + c] = u;
    }
    __syncthreads();

    int wave = tid >> 6, lane = tid & 63;
    int ln = lane & 15, quad = lane >> 4;
    int rowbase = wave * 32;

    short8 af[2][4];
#pragma unroll
    for (int m = 0; m < 2; ++m)
#pragma unroll
        for (int kt = 0; kt < 4; ++kt)
            af[m][kt] = *(const short8*)&sA[(rowbase + m * 16 + ln) * LP_RS + kt * 32 + quad * 8];

    float4v acc[2][8];
#pragma unroll
    for (int m = 0; m < 2; ++m)
#pragma unroll
        for (int n = 0; n < 8; ++n)
            acc[m][n] = float4v{0.f, 0.f, 0.f, 0.f};

#pragma unroll
    for (int n = 0; n < 8; ++n) {
#pragma unroll
        for (int kt = 0; kt < 4; ++kt) {
            short8 bf = *(const short8*)&sW[(n * 16 + ln) * LP_RS + kt * 32 + quad * 8];
            acc[0][n] = __builtin_amdgcn_mfma_f32_16x16x32_bf16(af[0][kt], bf, acc[0][n], 0, 0, 0);
            acc[1][n] = __builtin_amdgcn_mfma_f32_16x16x32_bf16(af[1][kt], bf, acc[1][n], 0, 0, 0);
        }
    }

    // epilogue: store H bf16 (C/D layout: col=ln, row=quad*4+reg) + fused scores
    float asr[8], adr[8];
#pragma unroll
    for (int n = 0; n < 8; ++n) {
        asr[n] = a_src[n * 16 + ln];
        adr[n] = a_dst[n * 16 + ln];
    }
#pragma unroll
    for (int m = 0; m < 2; ++m) {
        int rb = r0 + rowbase + m * 16 + quad * 4;
#pragma unroll
        for (int n = 0; n < 8; ++n) {
            int col = n * 16 + ln;
            float4v a = acc[m][n];
            if (rb + 0 < N) H[(size_t)(rb + 0) * 128 + col] = f2bf(a[0]);
            if (rb + 1 < N) H[(size_t)(rb + 1) * 128 + col] = f2bf(a[1]);
            if (rb + 2 < N) H[(size_t)(rb + 2) * 128 + col] = f2bf(a[2]);
            if (rb + 3 < N) H[(size_t)(rb + 3) * 128 + col] = f2bf(a[3]);
        }
#pragma unroll
        for (int r = 0; r < 4; ++r) {
            float ps = 0.f, pd = 0.f;
#pragma unroll
            for (int n = 0; n < 8; ++n) {
                float v = acc[m][n][r];
                ps = fmaf(v, asr[n], ps);
                pd = fmaf(v, adr[n], pd);
            }
#pragma unroll
            for (int o = 1; o < 16; o <<= 1) {
                ps += __shfl_xor(ps, o);
                pd += __shfl_xor(pd, o);
            }
            int row = rb + r;
            if (ln == 0 && row < N) { s_src[row] = ps; s_dst[row] = pd; }
        }
    }
}

// D3: gemm1 (blocks < gblk) overlapped with CSR fill (blocks >= gblk)
__global__ __launch_bounds__(256) void gemm1_fill(
    const void* __restrict__ Xv, const unsigned short* __restrict__ WT,
    const float* __restrict__ a_src, const float* __restrict__ a_dst,
    unsigned short* __restrict__ H, float* __restrict__ s_src,
    float* __restrict__ s_dst, int N, int gblk,
    const int* __restrict__ bcur, const unsigned int* __restrict__ bucket,
    int* __restrict__ gcnt, int* __restrict__ offs, int* __restrict__ ends,
    int* __restrict__ csr) {
    __shared__ uint4 smem[4352];  // 69632 B: gemm sA+sW, or fill rec/cnt/sc
    int b = blockIdx.x;
    if (b < gblk) {
        unsigned short* sA = (unsigned short*)smem;
        gemm_body<false>(sA, sA + 128 * LP_RS, b, Xv, WT, a_src, a_dst,
                         H, s_src, s_dst, N);
    } else {
        fill_body((char*)smem, b - gblk, bcur, bucket, gcnt, offs, ends, csr, N);
    }
}

// standalone gemm for conv2
template <bool BF16_IN>
__global__ __launch_bounds__(256) void gemm_mfma(
    const void* __restrict__ Xv, const unsigned short* __restrict__ WT,
    const float* __restrict__ a_src, const float* __restrict__ a_dst,
    unsigned short* __restrict__ H, float* __restrict__ s_src,
    float* __restrict__ s_dst, int N) {
    __shared__ uint4 smem[4352];
    unsigned short* sA = (unsigned short*)smem;
    gemm_body<BF16_IN>(sA, sA + 128 * LP_RS, blockIdx.x, Xv, WT, a_src, a_dst,
                       H, s_src, s_dst, N);
}

// ---------------------------------------------------------------------------
// Fused softmax + weighted gather (R16-proven, FINAL): TWO nodes per wave
// (32-lane halves, 4 ch/lane ushort4). Per 32-edge chunk: lane hl computes
// w=exp(leakyrelu(s_src[src]+sd)) (single-sweep softmax, shift-invariant —
// R11; s_src 200KB L2-resident), broadcast via __shfl, consumed 8-deep.
// 6 variants (R6/R7/R12/R19/R21/R22) all regressed or were neutral.
// ---------------------------------------------------------------------------
__global__ __launch_bounds__(256) void gat_gather(const unsigned short* __restrict__ H,
                                                  const int* __restrict__ offs,
                                                  const int* __restrict__ ends,
                                                  const int* __restrict__ csr,
                                                  const float* __restrict__ s_src,
                                                  const float* __restrict__ s_dst,
                                                  const float* __restrict__ bias,
                                                  const float* __restrict__ bn_scale,
                                                  const float* __restrict__ bn_shift,
                                                  int do_bn_relu,
                                                  unsigned short* __restrict__ out, int N) {
    int wave = threadIdx.x >> 6, lane = threadIdx.x & 63;
    int half = lane >> 5, hl = lane & 31;
    int node = blockIdx.x * 8 + wave * 2 + half;
    if (node >= N) return;
    int c0 = hl * 4;
    int beg = offs[node], end = ends[node];
    float sd = s_dst[node];

    float a0 = 0.f, a1 = 0.f, a2 = 0.f, a3 = 0.f;
    float sw = 0.f;
    for (int chunk = beg; chunk < end; chunk += 32) {
        int i = chunk + hl;
        int sidx = 0;
        float w = 0.f;
        if (i < end) {
            sidx = csr[i];
            float e = s_src[sidx] + sd;
            e = (e >= 0.f) ? e : NEG_SLOPE * e;
            w = expf(e);
        }
        sw += w;
        int cnt = end - chunk;
        if (cnt > 32) cnt = 32;
        int u = 0;
        for (; u + 8 <= cnt; u += 8) {
            int s[8]; float ww[8]; ushort4 hv[8];
#pragma unroll
            for (int j = 0; j < 8; ++j) {
                s[j]  = __shfl(sidx, u + j, 32);
                ww[j] = __shfl(w, u + j, 32);
            }
#pragma unroll
            for (int j = 0; j < 8; ++j)
                hv[j] = *(const ushort4*)&H[(size_t)s[j] * 128 + c0];
#pragma unroll
            for (int j = 0; j < 8; ++j) {
                a0 = fmaf(ww[j], bf2f(hv[j].x), a0);
                a1 = fmaf(ww[j], bf2f(hv[j].y), a1);
                a2 = fmaf(ww[j], bf2f(hv[j].z), a2);
                a3 = fmaf(ww[j], bf2f(hv[j].w), a3);
            }
        }
        for (; u + 4 <= cnt; u += 4) {
            int s[4]; float ww[4]; ushort4 hv[4];
#pragma unroll
            for (int j = 0; j < 4; ++j) {
                s[j]  = __shfl(sidx, u + j, 32);
                ww[j] = __shfl(w, u + j, 32);
            }
#pragma unroll
            for (int j = 0; j < 4; ++j)
                hv[j] = *(const ushort4*)&H[(size_t)s[j] * 128 + c0];
#pragma unroll
            for (int j = 0; j < 4; ++j) {
                a0 = fmaf(ww[j], bf2f(hv[j].x), a0);
                a1 = fmaf(ww[j], bf2f(hv[j].y), a1);
                a2 = fmaf(ww[j], bf2f(hv[j].z), a2);
                a3 = fmaf(ww[j], bf2f(hv[j].w), a3);
            }
        }
        for (; u < cnt; ++u) {
            int sj = __shfl(sidx, u, 32);
            float wj = __shfl(w, u, 32);
            ushort4 hv = *(const ushort4*)&H[(size_t)sj * 128 + c0];
            a0 = fmaf(wj, bf2f(hv.x), a0);
            a1 = fmaf(wj, bf2f(hv.y), a1);
            a2 = fmaf(wj, bf2f(hv.z), a2);
            a3 = fmaf(wj, bf2f(hv.w), a3);
        }
    }
#pragma unroll
    for (int o = 16; o; o >>= 1) sw += __shfl_xor(sw, o);
    float inv = 1.f / (sw + 1e-16f);

    float o0 = a0 * inv + bias[c0 + 0];
    float o1 = a1 * inv + bias[c0 + 1];
    float o2 = a2 * inv + bias[c0 + 2];
    float o3 = a3 * inv + bias[c0 + 3];
    if (do_bn_relu) {
        o0 = fmaxf(o0 * bn_scale[c0 + 0] + bn_shift[c0 + 0], 0.f);
        o1 = fmaxf(o1 * bn_scale[c0 + 1] + bn_shift[c0 + 1], 0.f);
        o2 = fmaxf(o2 * bn_scale[c0 + 2] + bn_shift[c0 + 2], 0.f);
        o3 = fmaxf(o3 * bn_scale[c0 + 3] + bn_shift[c0 + 3], 0.f);
    }
    ushort4 ov;
    ov.x = f2bf(o0); ov.y = f2bf(o1); ov.z = f2bf(o2); ov.w = f2bf(o3);
    *(ushort4*)&out[(size_t)node * 128 + c0] = ov;
}

// ---------------------------------------------------------------------------
// Link predictor v4 (R23): query-bucketed + XCD-colocated. 4 sibling blocks
// per bucket, all at blockIdx ≡ b (mod 8) so the round-robin block->XCD
// mapping puts them on one XCD: the bucket's 256 A-rows (64KB) stay L2-hot
// (~4 refs/row). e1 embedded in the record (no dependent E1[q] load).
// Per-wave 32-query tile pipeline = R10/R18-proven MFMA structure.
// ---------------------------------------------------------------------------
__global__ __launch_bounds__(512) void link_pred_mfma(
    const unsigned short* __restrict__ X,   // bf16 x2 [N][128]
    const int* __restrict__ qcur,
    const unsigned long long* __restrict__ qbucket,
    const unsigned short* __restrict__ WTg, // [n][k] bf16
    const float* __restrict__ bp1,
    const float* __restrict__ Wp2,
    const float* __restrict__ bp2_p,
    float* __restrict__ out, int nb)
{
    __shared__ unsigned short sW[128 * LP_RS];
    int tid = threadIdx.x;
    int wave = tid >> 6, lane = tid & 63;
    int ln = lane & 15, quad = lane >> 4;

    int x = blockIdx.x & 7;        // XCD home (round-robin heuristic)
    int g = blockIdx.x >> 3;
    int b = (g >> 2) * 8 + x;      // bucket; 4 siblings (k=0..3) share it
    int k = g & 3;
    if (b >= nb) return;

    // stage Wp1^T (512 threads -> 4 iters)
#pragma unroll
    for (int it = 0; it < 4; ++it) {
        int idx = it * 4096 + tid * 8;
        int n = idx >> 7, kk = idx & 127;
        *(short8*)&sW[n * LP_RS + kk] = *(const short8*)&WTg[idx];
    }

    float bias[8], w2c[8];
#pragma unroll
    for (int n = 0; n < 8; ++n) {
        bias[n] = bp1[n * 16 + ln];
        w2c[n] = Wp2[n * 16 + ln];
    }
    float b2 = bp2_p[0];

    int cnt = qcur[b];
    if (cnt < 0) cnt = 0;
    if (cnt > QB_CAP) cnt = QB_CAP;
    int tiles = (cnt + 31) >> 5;
    const unsigned long long* qb = &qbucket[(size_t)b * QB_CAP];

    __syncthreads();

    // sibling k takes tiles ≡ k (mod 4); waves stride within that set
    for (int t = k + 4 * wave; t < tiles; t += 32) {
        // 1. records: 16 queries per m, replicated across quads
        int q[2], ea[2], eb[2];
#pragma unroll
        for (int m = 0; m < 2; ++m) {
            int s = t * 32 + m * 16 + ln;
            bool val = s < cnt;
            unsigned long long r = qb[val ? s : 0];
            q[m]  = val ? (int)(r & 0xffffffu) : -1;
            ea[m] = (b << 8) | (int)((r >> 24) & 255u);
            eb[m] = (int)(r >> 32);
        }

        // 2. issue ALL 16 X-row loads before any conversion
        short8 ra[2][4], rb[2][4];
#pragma unroll
        for (int m = 0; m < 2; ++m) {
            const unsigned short* pa = &X[(size_t)ea[m] * 128 + quad * 8];
            const unsigned short* pb = &X[(size_t)eb[m] * 128 + quad * 8];
#pragma unroll
            for (int kt = 0; kt < 4; ++kt) {
                ra[m][kt] = *(const short8*)(pa + kt * 32);
                rb[m][kt] = *(const short8*)(pb + kt * 32);
            }
        }

        // 3. convert products to bf16 A-fragments (packed cvt)
        short8 af[2][4];
#pragma unroll
        for (int m = 0; m < 2; ++m) {
#pragma unroll
            for (int kt = 0; kt < 4; ++kt) {
                short8 p;
#pragma unroll
                for (int j = 0; j < 8; j += 2) {
                    float p0 = bf2f((unsigned short)ra[m][kt][j]) *
                               bf2f((unsigned short)rb[m][kt][j]);
                    float p1 = bf2f((unsigned short)ra[m][kt][j + 1]) *
                               bf2f((unsigned short)rb[m][kt][j + 1]);
                    __hip_bfloat162 h2 = __float22bfloat162_rn(make_float2(p0, p1));
                    unsigned pr;
                    memcpy(&pr, &h2, 4);
                    p[j]     = (short)(pr & 0xffffu);
                    p[j + 1] = (short)(pr >> 16);
                }
                af[m][kt] = p;
            }
        }

        // 4. MFMA (per-n consume) + fused epilogue
        float r0[2] = {0.f, 0.f}, r1[2] = {0.f, 0.f};
        float r2[2] = {0.f, 0.f}, r3[2] = {0.f, 0.f};
#pragma unroll
        for (int n = 0; n < 8; ++n) {
            float4v a0 = float4v{bias[n], bias[n], bias[n], bias[n]};
            float4v a1 = a0;
#pragma unroll
            for (int kt = 0; kt < 4; ++kt) {
                short8 bf = *(const short8*)&sW[(n * 16 + ln) * LP_RS + kt * 32 + quad * 8];
                a0 = __builtin_amdgcn_mfma_f32_16x16x32_bf16(af[0][kt], bf, a0, 0, 0, 0);
                a1 = __builtin_amdgcn_mfma_f32_16x16x32_bf16(af[1][kt], bf, a1, 0, 0, 0);
            }
            float w = w2c[n];
            r0[0] += fmaxf(a0[0], 0.f) * w;  r0[1] += fmaxf(a1[0], 0.f) * w;
            r1[0] += fmaxf(a0[1], 0.f) * w;  r1[1] += fmaxf(a1[1], 0.f) * w;
            r2[0] += fmaxf(a0[2], 0.f) * w;  r2[1] += fmaxf(a1[2], 0.f) * w;
            r3[0] += fmaxf(a0[3], 0.f) * w;  r3[1] += fmaxf(a1[3], 0.f) * w;
        }
#pragma unroll
        for (int m = 0; m < 2; ++m) {
#pragma unroll
            for (int o = 1; o < 16; o <<= 1) {
                r0[m] += __shfl_xor(r0[m], o);
                r1[m] += __shfl_xor(r1[m], o);
                r2[m] += __shfl_xor(r2[m], o);
                r3[m] += __shfl_xor(r3[m], o);
            }
            // row j = m*16 + quad*4 + r holds result r{r}[m] on this quad;
            // its q lives at group-lane quad*4+r (uniform across quads).
            int q0_ = __shfl(q[m], quad * 4 + 0, 16);
            int q1_ = __shfl(q[m], quad * 4 + 1, 16);
            int q2_ = __shfl(q[m], quad * 4 + 2, 16);
            int q3_ = __shfl(q[m], quad * 4 + 3, 16);
            if (ln == 0) {
                if (q0_ >= 0) out[q0_] = 1.f / (1.f + expf(-(r0[m] + b2)));
                if (q1_ >= 0) out[q1_] = 1.f / (1.f + expf(-(r1[m] + b2)));
                if (q2_ >= 0) out[q2_] = 1.f / (1.f + expf(-(r2[m] + b2)));
                if (q3_ >= 0) out[q3_] = 1.f / (1.f + expf(-(r3[m] + b2)));
            }
        }
    }
}

// ---------------------------------------------------------------------------
extern "C" void kernel_launch(void* const* d_in, const int* in_sizes, int n_in,
                              void* d_out, int out_size, void* d_ws, size_t ws_size,
                              hipStream_t stream) {
    const float* emb    = (const float*)d_in[0];
    const float* W1     = (const float*)d_in[1];
    const float* a_src1 = (const float*)d_in[2];
    const float* a_dst1 = (const float*)d_in[3];
    const float* b1     = (const float*)d_in[4];
    const float* gamma  = (const float*)d_in[5];
    const float* beta   = (const float*)d_in[6];
    const float* rmean  = (const float*)d_in[7];
    const float* rvar   = (const float*)d_in[8];
    const float* W2     = (const float*)d_in[9];
    const float* a_src2 = (const float*)d_in[10];
    const float* a_dst2 = (const float*)d_in[11];
    const float* b2     = (const float*)d_in[12];
    const float* Wp1    = (const float*)d_in[13];
    const float* bp1    = (const float*)d_in[14];
    const float* Wp2    = (const float*)d_in[15];
    const float* bp2    = (const float*)d_in[16];
    const int* edge_index = (const int*)d_in[17];
    const int* edges      = (const int*)d_in[18];

    const int N = in_sizes[0] / 128;
    const int E = in_sizes[17] / 2;
    const int Q = in_sizes[18] / 2;
    const int* src = edge_index;
    const int* dst = edge_index + E;
    const int* e0 = edges;
    const int* e1 = edges + Q;
    float* out = (float*)d_out;

    uintptr_t base = (uintptr_t)d_ws;
    size_t cur = 0;
    auto take = [&](size_t bytes) -> void* {
        void* p = (void*)(base + cur);
        cur += (bytes + 255) & ~(size_t)255;
        return p;
    };
    unsigned short* bufA = (unsigned short*)take((size_t)N * 128 * 2);  // H (bf16)
    unsigned short* bufB = (unsigned short*)take((size_t)N * 128 * 2);  // x (bf16)
    float* s_src  = (float*)take((size_t)N * 4);
    float* s_dst  = (float*)take((size_t)N * 4);
    float* bnsc   = (float*)take(128 * 4);
    float* bnsh   = (float*)take(128 * 4);
    int*   offs   = (int*)take((size_t)N * 4);
    int*   ends   = (int*)take((size_t)N * 4);
    int*   csr    = (int*)take((size_t)E * 4);
    unsigned short* wt1 = (unsigned short*)take(128 * 128 * 2);
    unsigned short* wt2 = (unsigned short*)take(128 * 128 * 2);
    unsigned short* wtp = (unsigned short*)take(128 * 128 * 2);
    int nb = (N + 255) / 256;  // buckets (196; must be <= 256)
    // bcur[0..nb-1] edge counters, bcur[nb] global csr cursor, then qcur[nb]
    int*   bcur   = (int*)take((size_t)(2 * nb + 1) * 4);
    int*   qcur   = bcur + nb + 1;
    unsigned int* bucket =
        (unsigned int*)take((size_t)nb * BK_CAP * 4);  // ~6.4 MB
    unsigned long long* qbucket =
        (unsigned long long*)take((size_t)nb * QB_CAP * 8);  // ~3.2 MB
    (void)ws_size; (void)n_in; (void)out_size;

    int nbs = (E + BK_EPB - 1) / BK_EPB;   // edge-scatter blocks (196)
    int nqs = (Q + BK_EPB - 1) / BK_EPB;   // query-scatter blocks (49)
    int gblk = (N + 127) / 128;

    // D1: zero all counters (2*nb+1 = 393 ints -> 2 blocks)
    zero_init<<<2, 256, 0, stream>>>(bcur, 2 * nb + 1);
    // D2: weight transpose + BN  ||  edge scatter  ||  query scatter
    prep_scatter<<<193 + nbs + nqs, 256, 0, stream>>>(
        W1, W2, Wp1, wt1, wt2, wtp,
        gamma, beta, rmean, rvar, bnsc, bnsh,
        src, dst, bcur, bucket, E,
        e0, e1, qcur, qbucket, Q, nbs);
    // D3: conv1 GEMM (+scores)  ||  CSR fill
    gemm1_fill<<<gblk + nb, 256, 0, stream>>>(emb, wt1, a_src1, a_dst1,
                                              bufA, s_src, s_dst, N, gblk,
                                              bcur, bucket, &bcur[nb],
                                              offs, ends, csr);
    // D4: gather1 + BN + ReLU
    gat_gather<<<(N + 7) / 8, 256, 0, stream>>>(bufA, offs, ends, csr, s_src, s_dst,
                                                b1, bnsc, bnsh, 1, bufB, N);
    // D5: conv2 GEMM (+scores)
    gemm_mfma<true><<<gblk, 256, 0, stream>>>(bufB, wt2, a_src2, a_dst2, bufA, s_src, s_dst, N);
    // D6: gather2
    gat_gather<<<(N + 7) / 8, 256, 0, stream>>>(bufA, offs, ends, csr, s_src, s_dst,
                                                b2, nullptr, nullptr, 0, bufB, N);
    // D7: link predictor (bucketed; 8 XCD lanes x ceil(nb/8) slots x 4 siblings)
    int lblk = 8 * ((nb + 7) / 8) * 4;
    link_pred_mfma<<<lblk, 512, 0, stream>>>(bufB, qcur, qbucket, wtp,
                                             bp1, Wp2, bp2, out, nb);
}

// Round 9
// 236.440 us; speedup vs baseline: 1.0536x; 1.0536x over previous
//
#include <hip/hip_runtime.h>
#include <hip/hip_bf16.h>
#include <math.h>
#include <stdint.h>
#include <string.h>

#define NEG_SLOPE 0.2f
#define BN_EPS 1e-5f

typedef __attribute__((ext_vector_type(8))) short short8;
typedef __attribute__((ext_vector_type(4))) float float4v;

static __device__ __forceinline__ unsigned short f2bf(float f) {
    union { float f; unsigned u; } v; v.f = f;
    unsigned r = (v.u + 0x7fffu + ((v.u >> 16) & 1u)) >> 16;  // RNE
    return (unsigned short)r;
}
static __device__ __forceinline__ float bf2f(unsigned short u) {
    union { unsigned u; float f; } v; v.u = ((unsigned)u) << 16;
    return v.f;
}

// ---------------------------------------------------------------------------
// R24 = R18 exact (proven 238.2 us best) + BK_EPB 4096->2048 (2x scatter
// parallelism for the LDS-atomic-latency-bound scatter phase).
// Closed explorations: gather inner loop (7 attempts <= 0: R6/R7/R12/R19/
// R21/R22), link_pred config (R20 1024-thr -4us, R23 bucketed -11us).
// R19 lesson: per-node work per-node. R21: never trade VGPR/occupancy for
// rows-in-flight in latency-bound kernels.
//   D1 = zero_init (in-kernel; hipMemsetAsync crashed graph capture in R17).
//   D2 = prep_scatter: W-transpose + BN consts || bucket_scatter.
//   D3 = gemm1_fill: conv1 GEMM (+scores) || bucket_offs_fill.
// Record: (dst&255)<<24 | src   (src < 2^24; N = 50000).
// ---------------------------------------------------------------------------
#define BK_CAP 8192          // slots per bucket (expected ~4096 for E/N=16)
#define BK_EPB 2048          // edges per block in scatter phase (R24: was 4096)
#define LP_RS 136            // LDS row stride in bf16 elements (272 bytes)

__global__ __launch_bounds__(256) void zero_init(int* __restrict__ p, int n) {
    int i = threadIdx.x + blockIdx.x * 256;
    if (i < n) p[i] = 0;
}

// ---- scatter body (blocks of prep_scatter with b >= 193) ------------------
static __device__ __forceinline__ void scatter_body(
    int* lcnt, int* lbase, int blk,
    const int* __restrict__ src, const int* __restrict__ dst,
    int* __restrict__ bcur, unsigned int* __restrict__ bucket, int E) {
    int t = threadIdx.x;
    int e0 = blk * BK_EPB;
    lcnt[t] = 0;
    __syncthreads();

    int es[8], ed[8];
#pragma unroll
    for (int u = 0; u < 8; ++u) {
        int i = e0 + u * 256 + t;
        if (i < E) {
            es[u] = src[i];
            ed[u] = dst[i];
            atomicAdd(&lcnt[ed[u] >> 8], 1);
        } else {
            ed[u] = -1;
        }
    }
    __syncthreads();
    int c = lcnt[t];
    if (c > 0) lbase[t] = atomicAdd(&bcur[t], c);
    __syncthreads();
    lcnt[t] = 0;
    __syncthreads();
#pragma unroll
    for (int u = 0; u < 8; ++u) {
        if (ed[u] >= 0) {
            int bin = ed[u] >> 8;
            int r = atomicAdd(&lcnt[bin], 1);
            int slot = lbase[bin] + r;
            if (slot < BK_CAP)
                bucket[(size_t)bin * BK_CAP + slot] =
                    ((unsigned)(ed[u] & 255) << 24) | (unsigned)es[u];
        }
    }
}

__global__ __launch_bounds__(256) void prep_scatter(
    const float* __restrict__ W1, const float* __restrict__ W2,
    const float* __restrict__ Wp1,
    unsigned short* __restrict__ wt1, unsigned short* __restrict__ wt2,
    unsigned short* __restrict__ wtp,
    const float* __restrict__ gamma, const float* __restrict__ beta,
    const float* __restrict__ rmean, const float* __restrict__ rvar,
    float* __restrict__ bnsc, float* __restrict__ bnsh,
    const int* __restrict__ src, const int* __restrict__ dst,
    int* __restrict__ bcur, unsigned int* __restrict__ bucket, int E) {
    __shared__ int lcnt[256];
    __shared__ int lbase[256];
    int b = blockIdx.x;
    if (b < 192) {
        const float* W = (b < 64) ? W1 : (b < 128) ? W2 : Wp1;
        unsigned short* WT = (b < 64) ? wt1 : (b < 128) ? wt2 : wtp;
        int idx = (b & 63) * 256 + threadIdx.x;  // 16384 per matrix
        int k = idx >> 7, n = idx & 127;
        WT[n * 128 + k] = f2bf(W[idx]);
    } else if (b == 192) {
        if (threadIdx.x < 128) {
            int c = threadIdx.x;
            float s = gamma[c] * rsqrtf(rvar[c] + BN_EPS);
            bnsc[c] = s;
            bnsh[c] = beta[c] - rmean[c] * s;
        }
    } else {
        scatter_body(lcnt, lbase, b - 193, src, dst, bcur, bucket, E);
    }
}

// ---- fill body (blocks of gemm1_fill with b >= gblk) -----------------------
// LDS carved from the gemm's 69.6 KB block: rec 32 KB | cnt 1 KB | sc 1 KB | base
static __device__ __forceinline__ void fill_body(
    char* base, int b,
    const int* __restrict__ bcur, const unsigned int* __restrict__ bucket,
    int* __restrict__ gcnt,
    int* __restrict__ offs, int* __restrict__ ends,
    int* __restrict__ csr, int N) {
    unsigned int* rec = (unsigned int*)base;                 // BK_CAP * 4
    int* cnt = (int*)(base + BK_CAP * 4);
    int* sc  = cnt + 256;
    int* pb  = sc + 256;
    int t = threadIdx.x;
    const unsigned int* gb = &bucket[(size_t)b * BK_CAP];
    cnt[t] = 0;
    int c = bcur[b];
    if (c < 0) c = 0;          // defensive: never trust a poisoned counter
    if (c > BK_CAP) c = BK_CAP;
    if (t == 0) *pb = atomicAdd(gcnt, c);
    for (int i = t; i < c; i += 256) rec[i] = gb[i];
    __syncthreads();
    for (int i = t; i < c; i += 256) atomicAdd(&cnt[rec[i] >> 24], 1);
    __syncthreads();
    int v = cnt[t];
    sc[t] = v;
    __syncthreads();
    for (int d = 1; d < 256; d <<= 1) {
        int u = (t >= d) ? sc[t - d] : 0;
        __syncthreads();
        sc[t] += u;
        __syncthreads();
    }
    int myoff = *pb + sc[t] - v;
    int node = (b << 8) + t;
    if (node < N) {
        offs[node] = myoff;
        ends[node] = myoff + v;
    }
    cnt[t] = myoff;  // reuse as cursors
    __syncthreads();
    for (int i = t; i < c; i += 256) {
        unsigned int rv = rec[i];
        int r = atomicAdd(&cnt[rv >> 24], 1);
        csr[r] = (int)(rv & 0xffffffu);
    }
}

// ---------------------------------------------------------------------------
// H(bf16) = X @ W via MFMA bf16 (fp32 accum), node_scores fused in epilogue
// (per-node cost, amortized over N — R19 lesson).
// ---------------------------------------------------------------------------
template <bool BF16_IN>
static __device__ __forceinline__ void gemm_body(
    unsigned short* sA, unsigned short* sW, int bid,
    const void* __restrict__ Xv,
    const unsigned short* __restrict__ WT,  // [n][k] bf16 (pre-transposed)
    const float* __restrict__ a_src, const float* __restrict__ a_dst,
    unsigned short* __restrict__ H,         // bf16 out
    float* __restrict__ s_src, float* __restrict__ s_dst, int N)
{
    const float* Xf = (const float*)Xv;
    const unsigned short* Xh = (const unsigned short*)Xv;
    int tid = threadIdx.x;
    int r0 = bid * 128;

#pragma unroll
    for (int it = 0; it < 8; ++it) {
        int idx = it * 2048 + tid * 8;
        int n = idx >> 7, k = idx & 127;
        *(short8*)&sW[n * LP_RS + k] = *(const short8*)&WT[idx];
    }
#pragma unroll
    for (int it = 0; it < 16; ++it) {
        int r = it * 8 + (tid >> 5);
        int c = (tid & 31) * 4;
        int row = r0 + r;
        ushort4 u = make_ushort4(0, 0, 0, 0);
        if (row < N) {
            if (BF16_IN) {
                u = *(const ushort4*)&Xh[(size_t)row * 128 + c];
            } else {
                float4 x = *(const float4*)&Xf[(size_t)row * 128 + c];
                u.x = f2bf(x.x); u.y = f2bf(x.y); u.z = f2bf(x.z); u.w = f2bf(x.w);
            }
        }
        *(ushort4*)&sA[r * LP_RS + c] = u;
    }
    __syncthreads();

    int wave = tid >> 6, lane = tid & 63;
    int ln = lane & 15, quad = lane >> 4;
    int rowbase = wave * 32;

    short8 af[2][4];
#pragma unroll
    for (int m = 0; m < 2; ++m)
#pragma unroll
        for (int kt = 0; kt < 4; ++kt)
            af[m][kt] = *(const short8*)&sA[(rowbase + m * 16 + ln) * LP_RS + kt * 32 + quad * 8];

    float4v acc[2][8];
#pragma unroll
    for (int m = 0; m < 2; ++m)
#pragma unroll
        for (int n = 0; n < 8; ++n)
            acc[m][n] = float4v{0.f, 0.f, 0.f, 0.f};

#pragma unroll
    for (int n = 0; n < 8; ++n) {
#pragma unroll
        for (int kt = 0; kt < 4; ++kt) {
            short8 bf = *(const short8*)&sW[(n * 16 + ln) * LP_RS + kt * 32 + quad * 8];
            acc[0][n] = __builtin_amdgcn_mfma_f32_16x16x32_bf16(af[0][kt], bf, acc[0][n], 0, 0, 0);
            acc[1][n] = __builtin_amdgcn_mfma_f32_16x16x32_bf16(af[1][kt], bf, acc[1][n], 0, 0, 0);
        }
    }

    // epilogue: store H bf16 (C/D layout: col=ln, row=quad*4+reg) + fused scores
    float asr[8], adr[8];
#pragma unroll
    for (int n = 0; n < 8; ++n) {
        asr[n] = a_src[n * 16 + ln];
        adr[n] = a_dst[n * 16 + ln];
    }
#pragma unroll
    for (int m = 0; m < 2; ++m) {
        int rb = r0 + rowbase + m * 16 + quad * 4;
#pragma unroll
        for (int n = 0; n < 8; ++n) {
            int col = n * 16 + ln;
            float4v a = acc[m][n];
            if (rb + 0 < N) H[(size_t)(rb + 0) * 128 + col] = f2bf(a[0]);
            if (rb + 1 < N) H[(size_t)(rb + 1) * 128 + col] = f2bf(a[1]);
            if (rb + 2 < N) H[(size_t)(rb + 2) * 128 + col] = f2bf(a[2]);
            if (rb + 3 < N) H[(size_t)(rb + 3) * 128 + col] = f2bf(a[3]);
        }
#pragma unroll
        for (int r = 0; r < 4; ++r) {
            float ps = 0.f, pd = 0.f;
#pragma unroll
            for (int n = 0; n < 8; ++n) {
                float v = acc[m][n][r];
                ps = fmaf(v, asr[n], ps);
                pd = fmaf(v, adr[n], pd);
            }
#pragma unroll
            for (int o = 1; o < 16; o <<= 1) {
                ps += __shfl_xor(ps, o);
                pd += __shfl_xor(pd, o);
            }
            int row = rb + r;
            if (ln == 0 && row < N) { s_src[row] = ps; s_dst[row] = pd; }
        }
    }
}

// D3: gemm1 (blocks < gblk) overlapped with CSR fill (blocks >= gblk)
__global__ __launch_bounds__(256) void gemm1_fill(
    const void* __restrict__ Xv, const unsigned short* __restrict__ WT,
    const float* __restrict__ a_src, const float* __restrict__ a_dst,
    unsigned short* __restrict__ H, float* __restrict__ s_src,
    float* __restrict__ s_dst, int N, int gblk,
    const int* __restrict__ bcur, const unsigned int* __restrict__ bucket,
    int* __restrict__ gcnt, int* __restrict__ offs, int* __restrict__ ends,
    int* __restrict__ csr) {
    __shared__ uint4 smem[4352];  // 69632 B: gemm sA+sW, or fill rec/cnt/sc
    int b = blockIdx.x;
    if (b < gblk) {
        unsigned short* sA = (unsigned short*)smem;
        gemm_body<false>(sA, sA + 128 * LP_RS, b, Xv, WT, a_src, a_dst,
                         H, s_src, s_dst, N);
    } else {
        fill_body((char*)smem, b - gblk, bcur, bucket, gcnt, offs, ends, csr, N);
    }
}

// standalone gemm for conv2
template <bool BF16_IN>
__global__ __launch_bounds__(256) void gemm_mfma(
    const void* __restrict__ Xv, const unsigned short* __restrict__ WT,
    const float* __restrict__ a_src, const float* __restrict__ a_dst,
    unsigned short* __restrict__ H, float* __restrict__ s_src,
    float* __restrict__ s_dst, int N) {
    __shared__ uint4 smem[4352];
    unsigned short* sA = (unsigned short*)smem;
    gemm_body<BF16_IN>(sA, sA + 128 * LP_RS, blockIdx.x, Xv, WT, a_src, a_dst,
                       H, s_src, s_dst, N);
}

// ---------------------------------------------------------------------------
// Fused softmax + weighted gather (R16-proven, FINAL): TWO nodes per wave
// (32-lane halves, 4 ch/lane ushort4). Per 32-edge chunk: lane hl computes
// w=exp(leakyrelu(s_src[src]+sd)) (single-sweep softmax, shift-invariant —
// R11; s_src 200KB L2-resident), broadcast via __shfl, consumed 8-deep.
// 7 variants (R6/R7/R12/R19/R21/R22) all regressed or were neutral.
// ---------------------------------------------------------------------------
__global__ __launch_bounds__(256) void gat_gather(const unsigned short* __restrict__ H,
                                                  const int* __restrict__ offs,
                                                  const int* __restrict__ ends,
                                                  const int* __restrict__ csr,
                                                  const float* __restrict__ s_src,
                                                  const float* __restrict__ s_dst,
                                                  const float* __restrict__ bias,
                                                  const float* __restrict__ bn_scale,
                                                  const float* __restrict__ bn_shift,
                                                  int do_bn_relu,
                                                  unsigned short* __restrict__ out, int N) {
    int wave = threadIdx.x >> 6, lane = threadIdx.x & 63;
    int half = lane >> 5, hl = lane & 31;
    int node = blockIdx.x * 8 + wave * 2 + half;
    if (node >= N) return;
    int c0 = hl * 4;
    int beg = offs[node], end = ends[node];
    float sd = s_dst[node];

    float a0 = 0.f, a1 = 0.f, a2 = 0.f, a3 = 0.f;
    float sw = 0.f;
    for (int chunk = beg; chunk < end; chunk += 32) {
        int i = chunk + hl;
        int sidx = 0;
        float w = 0.f;
        if (i < end) {
            sidx = csr[i];
            float e = s_src[sidx] + sd;
            e = (e >= 0.f) ? e : NEG_SLOPE * e;
            w = expf(e);
        }
        sw += w;
        int cnt = end - chunk;
        if (cnt > 32) cnt = 32;
        int u = 0;
        for (; u + 8 <= cnt; u += 8) {
            int s[8]; float ww[8]; ushort4 hv[8];
#pragma unroll
            for (int j = 0; j < 8; ++j) {
                s[j]  = __shfl(sidx, u + j, 32);
                ww[j] = __shfl(w, u + j, 32);
            }
#pragma unroll
            for (int j = 0; j < 8; ++j)
                hv[j] = *(const ushort4*)&H[(size_t)s[j] * 128 + c0];
#pragma unroll
            for (int j = 0; j < 8; ++j) {
                a0 = fmaf(ww[j], bf2f(hv[j].x), a0);
                a1 = fmaf(ww[j], bf2f(hv[j].y), a1);
                a2 = fmaf(ww[j], bf2f(hv[j].z), a2);
                a3 = fmaf(ww[j], bf2f(hv[j].w), a3);
            }
        }
        for (; u + 4 <= cnt; u += 4) {
            int s[4]; float ww[4]; ushort4 hv[4];
#pragma unroll
            for (int j = 0; j < 4; ++j) {
                s[j]  = __shfl(sidx, u + j, 32);
                ww[j] = __shfl(w, u + j, 32);
            }
#pragma unroll
            for (int j = 0; j < 4; ++j)
                hv[j] = *(const ushort4*)&H[(size_t)s[j] * 128 + c0];
#pragma unroll
            for (int j = 0; j < 4; ++j) {
                a0 = fmaf(ww[j], bf2f(hv[j].x), a0);
                a1 = fmaf(ww[j], bf2f(hv[j].y), a1);
                a2 = fmaf(ww[j], bf2f(hv[j].z), a2);
                a3 = fmaf(ww[j], bf2f(hv[j].w), a3);
            }
        }
        for (; u < cnt; ++u) {
            int sj = __shfl(sidx, u, 32);
            float wj = __shfl(w, u, 32);
            ushort4 hv = *(const ushort4*)&H[(size_t)sj * 128 + c0];
            a0 = fmaf(wj, bf2f(hv.x), a0);
            a1 = fmaf(wj, bf2f(hv.y), a1);
            a2 = fmaf(wj, bf2f(hv.z), a2);
            a3 = fmaf(wj, bf2f(hv.w), a3);
        }
    }
#pragma unroll
    for (int o = 16; o; o >>= 1) sw += __shfl_xor(sw, o);
    float inv = 1.f / (sw + 1e-16f);

    float o0 = a0 * inv + bias[c0 + 0];
    float o1 = a1 * inv + bias[c0 + 1];
    float o2 = a2 * inv + bias[c0 + 2];
    float o3 = a3 * inv + bias[c0 + 3];
    if (do_bn_relu) {
        o0 = fmaxf(o0 * bn_scale[c0 + 0] + bn_shift[c0 + 0], 0.f);
        o1 = fmaxf(o1 * bn_scale[c0 + 1] + bn_shift[c0 + 1], 0.f);
        o2 = fmaxf(o2 * bn_scale[c0 + 2] + bn_shift[c0 + 2], 0.f);
        o3 = fmaxf(o3 * bn_scale[c0 + 3] + bn_shift[c0 + 3], 0.f);
    }
    ushort4 ov;
    ov.x = f2bf(o0); ov.y = f2bf(o1); ov.z = f2bf(o2); ov.w = f2bf(o3);
    *(ushort4*)&out[(size_t)node * 128 + c0] = ov;
}

// ---------------------------------------------------------------------------
// Link predictor v3.1 (R18-proven FINAL): one 32-query tile per wave, 8 waves
// per block (512 threads). R20: 1024-thr regressed; R23: bucketing regressed.
// Dependency-ordered issue; no min-waves clamp (R4 spill lesson).
// ---------------------------------------------------------------------------
__global__ __launch_bounds__(512) void link_pred_mfma(
    const unsigned short* __restrict__ X,   // bf16 x2 [N][128]
    const int* __restrict__ E0, const int* __restrict__ E1,
    const unsigned short* __restrict__ WTg, // [n][k] bf16
    const float* __restrict__ bp1,
    const float* __restrict__ Wp2,
    const float* __restrict__ bp2_p,
    float* __restrict__ out, int Q)
{
    __shared__ unsigned short sW[128 * LP_RS];
    int tid = threadIdx.x;
    int wave = tid >> 6, lane = tid & 63;
    int ln = lane & 15, quad = lane >> 4;

    int tile = blockIdx.x * 8 + wave;
    int qbase = tile * 32;

    // 1. endpoint index loads first — head of the longest dependency chain
    int ea[2], eb[2];
#pragma unroll
    for (int m = 0; m < 2; ++m) {
        int q = qbase + m * 16 + ln;
        if (q >= Q) q = Q - 1;  // clamp; stores are guarded
        ea[m] = E0[q];
        eb[m] = E1[q];
    }

    // 2. stage Wp1^T (512 threads -> 4 iters; loads overlap idx latency)
#pragma unroll
    for (int it = 0; it < 4; ++it) {
        int idx = it * 4096 + tid * 8;
        int n = idx >> 7, k = idx & 127;
        *(short8*)&sW[n * LP_RS + k] = *(const short8*)&WTg[idx];
    }

    // 3. issue ALL 16 X-row loads before any conversion
    short8 ra[2][4], rb[2][4];
#pragma unroll
    for (int m = 0; m < 2; ++m) {
        const unsigned short* pa = &X[(size_t)ea[m] * 128 + quad * 8];
        const unsigned short* pb = &X[(size_t)eb[m] * 128 + quad * 8];
#pragma unroll
        for (int kt = 0; kt < 4; ++kt) {
            ra[m][kt] = *(const short8*)(pa + kt * 32);
            rb[m][kt] = *(const short8*)(pb + kt * 32);
        }
    }

    float bias[8], w2c[8];
#pragma unroll
    for (int n = 0; n < 8; ++n) {
        bias[n] = bp1[n * 16 + ln];
        w2c[n] = Wp2[n * 16 + ln];
    }
    float b2 = bp2_p[0];

    __syncthreads();

    // 4. convert products to bf16 A-fragments (packed cvt, 2 elems/op)
    short8 af[2][4];
#pragma unroll
    for (int m = 0; m < 2; ++m) {
#pragma unroll
        for (int kt = 0; kt < 4; ++kt) {
            short8 p;
#pragma unroll
            for (int j = 0; j < 8; j += 2) {
                float p0 = bf2f((unsigned short)ra[m][kt][j]) *
                           bf2f((unsigned short)rb[m][kt][j]);
                float p1 = bf2f((unsigned short)ra[m][kt][j + 1]) *
                           bf2f((unsigned short)rb[m][kt][j + 1]);
                __hip_bfloat162 h2 = __float22bfloat162_rn(make_float2(p0, p1));
                unsigned pr;
                memcpy(&pr, &h2, 4);
                p[j]     = (short)(pr & 0xffffu);
                p[j + 1] = (short)(pr >> 16);
            }
            af[m][kt] = p;
        }
    }

    // 5. MFMA (per-n consume) + fused epilogue
    float r0[2] = {0.f, 0.f}, r1[2] = {0.f, 0.f}, r2[2] = {0.f, 0.f}, r3[2] = {0.f, 0.f};
#pragma unroll
    for (int n = 0; n < 8; ++n) {
        float4v a0 = float4v{bias[n], bias[n], bias[n], bias[n]};
        float4v a1 = a0;
#pragma unroll
        for (int kt = 0; kt < 4; ++kt) {
            short8 bf = *(const short8*)&sW[(n * 16 + ln) * LP_RS + kt * 32 + quad * 8];
            a0 = __builtin_amdgcn_mfma_f32_16x16x32_bf16(af[0][kt], bf, a0, 0, 0, 0);
            a1 = __builtin_amdgcn_mfma_f32_16x16x32_bf16(af[1][kt], bf, a1, 0, 0, 0);
        }
        float w = w2c[n];
        r0[0] += fmaxf(a0[0], 0.f) * w;  r0[1] += fmaxf(a1[0], 0.f) * w;
        r1[0] += fmaxf(a0[1], 0.f) * w;  r1[1] += fmaxf(a1[1], 0.f) * w;
        r2[0] += fmaxf(a0[2], 0.f) * w;  r2[1] += fmaxf(a1[2], 0.f) * w;
        r3[0] += fmaxf(a0[3], 0.f) * w;  r3[1] += fmaxf(a1[3], 0.f) * w;
    }
#pragma unroll
    for (int m = 0; m < 2; ++m) {
#pragma unroll
        for (int o = 1; o < 16; o <<= 1) {
            r0[m] += __shfl_xor(r0[m], o);
            r1[m] += __shfl_xor(r1[m], o);
            r2[m] += __shfl_xor(r2[m], o);
            r3[m] += __shfl_xor(r3[m], o);
        }
        if (ln == 0) {
            int rbase = qbase + m * 16 + quad * 4;
            float rv[4] = {r0[m], r1[m], r2[m], r3[m]};
#pragma unroll
            for (int r = 0; r < 4; ++r) {
                int q = rbase + r;
                if (q < Q) out[q] = 1.f / (1.f + expf(-(rv[r] + b2)));
            }
        }
    }
}

// ---------------------------------------------------------------------------
extern "C" void kernel_launch(void* const* d_in, const int* in_sizes, int n_in,
                              void* d_out, int out_size, void* d_ws, size_t ws_size,
                              hipStream_t stream) {
    const float* emb    = (const float*)d_in[0];
    const float* W1     = (const float*)d_in[1];
    const float* a_src1 = (const float*)d_in[2];
    const float* a_dst1 = (const float*)d_in[3];
    const float* b1     = (const float*)d_in[4];
    const float* gamma  = (const float*)d_in[5];
    const float* beta   = (const float*)d_in[6];
    const float* rmean  = (const float*)d_in[7];
    const float* rvar   = (const float*)d_in[8];
    const float* W2     = (const float*)d_in[9];
    const float* a_src2 = (const float*)d_in[10];
    const float* a_dst2 = (const float*)d_in[11];
    const float* b2     = (const float*)d_in[12];
    const float* Wp1    = (const float*)d_in[13];
    const float* bp1    = (const float*)d_in[14];
    const float* Wp2    = (const float*)d_in[15];
    const float* bp2    = (const float*)d_in[16];
    const int* edge_index = (const int*)d_in[17];
    const int* edges      = (const int*)d_in[18];

    const int N = in_sizes[0] / 128;
    const int E = in_sizes[17] / 2;
    const int Q = in_sizes[18] / 2;
    const int* src = edge_index;
    const int* dst = edge_index + E;
    const int* e0 = edges;
    const int* e1 = edges + Q;
    float* out = (float*)d_out;

    uintptr_t base = (uintptr_t)d_ws;
    size_t cur = 0;
    auto take = [&](size_t bytes) -> void* {
        void* p = (void*)(base + cur);
        cur += (bytes + 255) & ~(size_t)255;
        return p;
    };
    unsigned short* bufA = (unsigned short*)take((size_t)N * 128 * 2);  // H (bf16)
    unsigned short* bufB = (unsigned short*)take((size_t)N * 128 * 2);  // x (bf16)
    float* s_src  = (float*)take((size_t)N * 4);
    float* s_dst  = (float*)take((size_t)N * 4);
    float* bnsc   = (float*)take(128 * 4);
    float* bnsh   = (float*)take(128 * 4);
    int*   offs   = (int*)take((size_t)N * 4);
    int*   ends   = (int*)take((size_t)N * 4);
    int*   csr    = (int*)take((size_t)E * 4);
    unsigned short* wt1 = (unsigned short*)take(128 * 128 * 2);
    unsigned short* wt2 = (unsigned short*)take(128 * 128 * 2);
    unsigned short* wtp = (unsigned short*)take(128 * 128 * 2);
    int nb = (N + 255) / 256;  // dst-buckets (196; must be <= 256)
    int*   bcur   = (int*)take((size_t)(nb + 1) * 4);  // [nb] = global csr cursor
    unsigned int* bucket =
        (unsigned int*)take((size_t)nb * BK_CAP * 4);  // ~6.4 MB
    (void)ws_size; (void)n_in; (void)out_size;

    int nbs = (E + BK_EPB - 1) / BK_EPB;   // scatter blocks (391 at EPB=2048)
    int gblk = (N + 127) / 128;

    // D1: zero bucket counters + global csr cursor (in-kernel; no memset —
    // hipMemsetAsync under graph capture killed the container in R17)
    zero_init<<<1, 256, 0, stream>>>(bcur, nb + 1);
    // D2: weight transpose + BN consts  ||  bucket scatter
    prep_scatter<<<193 + nbs, 256, 0, stream>>>(W1, W2, Wp1, wt1, wt2, wtp,
                                                gamma, beta, rmean, rvar, bnsc, bnsh,
                                                src, dst, bcur, bucket, E);
    // D3: conv1 GEMM (+scores)  ||  CSR fill
    gemm1_fill<<<gblk + nb, 256, 0, stream>>>(emb, wt1, a_src1, a_dst1,
                                              bufA, s_src, s_dst, N, gblk,
                                              bcur, bucket, &bcur[nb],
                                              offs, ends, csr);
    // D4: gather1 + BN + ReLU
    gat_gather<<<(N + 7) / 8, 256, 0, stream>>>(bufA, offs, ends, csr, s_src, s_dst,
                                                b1, bnsc, bnsh, 1, bufB, N);
    // D5: conv2 GEMM (+scores)
    gemm_mfma<true><<<gblk, 256, 0, stream>>>(bufB, wt2, a_src2, a_dst2, bufA, s_src, s_dst, N);
    // D6: gather2
    gat_gather<<<(N + 7) / 8, 256, 0, stream>>>(bufA, offs, ends, csr, s_src, s_dst,
                                                b2, nullptr, nullptr, 0, bufB, N);
    // D7: link predictor
    int ntiles = (Q + 31) / 32;
    int lblk = (ntiles + 7) / 8;
    link_pred_mfma<<<lblk, 512, 0, stream>>>(bufB, e0, e1, wtp, bp1, Wp2, bp2, out, Q);
}